// Round 13
// baseline (252.631 us; speedup 1.0000x reference)
//
#include <hip/hip_runtime.h>
#include <cstdint>
#include <cstddef>

#define N_NODES 100000
#define N_EDGES 500000
#define IN_DIM  128
#define HID     512
#define N_CLS   40
#define N_SBLK  ((N_NODES + 255) / 256)   // 391 scan blocks
#define N_CNTB  ((N_EDGES + 255) / 256)   // 1954 count blocks
#define N_XBFB  12500                     // xbf blocks (3.2M float4)
#define N_PREPB 352                       // prep blocks

typedef short bf16x8 __attribute__((ext_vector_type(8)));
typedef float f32x4 __attribute__((ext_vector_type(4)));
typedef int   i32x2 __attribute__((ext_vector_type(2)));
typedef unsigned u32x2 __attribute__((ext_vector_type(2)));

__device__ inline unsigned short f2bf(float f) {
  unsigned u = __float_as_uint(f);
  u = u + 0x7fffu + ((u >> 16) & 1u);          // RNE
  return (unsigned short)(u >> 16);
}
__device__ inline float blo(unsigned u) { return __uint_as_float(u << 16); }
__device__ inline float bhi(unsigned u) { return __uint_as_float(u & 0xffff0000u); }

// fused: blocks [0,N_CNTB) count in-degrees; blocks [N_CNTB,..) convert x->bf16
__global__ __launch_bounds__(256) void k_count_xbf(const int* __restrict__ dst, int* __restrict__ cnt,
                                                   const float* __restrict__ x, unsigned* __restrict__ xb) {
  int b = blockIdx.x;
  if (b < N_CNTB) {
    int e = b * 256 + threadIdx.x;
    if (e < N_EDGES) atomicAdd(&cnt[dst[e]], 1);
  } else {
    int t = (b - N_CNTB) * 256 + threadIdx.x;  // 3.2M exact
    float4 v = ((const float4*)x)[t];
    u32x2 o;
    o.x = (unsigned)f2bf(v.x) | ((unsigned)f2bf(v.y) << 16);
    o.y = (unsigned)f2bf(v.z) | ((unsigned)f2bf(v.w) << 16);
    __builtin_nontemporal_store(o, (u32x2*)(xb + 2 * (size_t)t));
  }
}

// single-pass scan (decoupled lookback) fused with weight prep.
__global__ __launch_bounds__(256) void k_scan_prep(const int* __restrict__ cnt, unsigned* __restrict__ flags,
                                                   int* __restrict__ offsets, int* __restrict__ cursor,
                                                   float* __restrict__ dinv,
                                                   const float* __restrict__ W1, const float* __restrict__ W2,
                                                   unsigned short* __restrict__ W1F, unsigned short* __restrict__ W2F) {
  int b = blockIdx.x;
  if (b < N_SBLK) {
    __shared__ int s[256];
    __shared__ int base_sh;
    int i = b * 256 + threadIdx.x;
    int v = (i < N_NODES) ? cnt[i] : 0;
    s[threadIdx.x] = v;
    __syncthreads();
    #pragma unroll
    for (int off = 1; off < 256; off <<= 1) {
      int t = (threadIdx.x >= off) ? s[threadIdx.x - off] : 0;
      __syncthreads();
      s[threadIdx.x] += t;
      __syncthreads();
    }
    int incl = s[threadIdx.x];
    if (threadIdx.x == 0) {
      int total = s[255];
      if (b == 0) {
        atomicExch(&flags[0], (2u << 30) | (unsigned)total);
        base_sh = 0;
      } else {
        atomicExch(&flags[b], (1u << 30) | (unsigned)total);
        int base = 0, pred = b - 1;
        while (true) {
          unsigned f;
          do { f = atomicAdd(&flags[pred], 0u); } while ((f >> 30) == 0u);
          base += (int)(f & 0x3fffffffu);
          if ((f >> 30) == 2u) break;
          --pred;
        }
        atomicExch(&flags[b], (2u << 30) | (unsigned)(base + (unsigned)total));
        base_sh = base;
      }
    }
    __syncthreads();
    int gbase = base_sh;
    if (i < N_NODES) {
      int excl = gbase + incl - v;
      offsets[i] = excl;
      cursor[i]  = excl;
      dinv[i]    = rsqrtf((float)(v + 1));     // +1 self-loop
    }
    if (b == 0 && threadIdx.x == 0) offsets[N_NODES] = N_EDGES;   // sentinel
  } else {
    int t = (b - N_SBLK) * 256 + threadIdx.x;  // 90112 exact
    if (t < 65536) {
      int j = t & 7, lane = (t >> 3) & 63, rest = t >> 9;   // rest = c*4+s
      int s2 = rest & 3, c = rest >> 2;
      int k = s2 * 32 + (lane >> 4) * 8 + j;
      int n = c * 16 + (lane & 15);
      W1F[t] = f2bf(W1[k * HID + n]);
    } else {
      int u = t - 65536;                        // 24576
      int j = u & 7, lane = (u >> 3) & 63, rest = u >> 9;   // rest = gk*3+ct
      int ct = rest % 3, gk = rest / 3;
      int k = gk * 32 + (lane >> 4) * 8 + j;
      int col = ct * 16 + (lane & 15);
      W2F[u] = (col < N_CLS) ? f2bf(W2[k * N_CLS + col]) : (unsigned short)0;
    }
  }
}

// fill CSR with (src, norm) pairs
__global__ __launch_bounds__(256) void k_fill(const int* __restrict__ src, const int* __restrict__ dst,
                                              const float* __restrict__ dinv,
                                              int* __restrict__ cursor, int2* __restrict__ epair) {
  int e = blockIdx.x * 256 + threadIdx.x;
  if (e >= N_EDGES) return;
  int s = src[e], d = dst[e];
  int pos = atomicAdd(&cursor[d], 1);
  float nrm = dinv[s] * dinv[d];
  epair[pos] = make_int2(s, __float_as_int(nrm));
}

// ---------------- layer-1 aggregation (gather, bf16): Z1 = Ahat @ X ----------------
// ONE node per 32-lane half (row = 32 x uint2 = 256B); 2 nodes/wave.
// Branch-free 8-wide masked rounds: no serial remainder; inactive slots get norm=0, idx=0.
__global__ __launch_bounds__(256) void k_gather1(const uint2* __restrict__ xb, const i32x2* __restrict__ ep,
                                                 const int* __restrict__ offsets,
                                                 const float* __restrict__ dinv, unsigned* __restrict__ z1) {
  int lane = threadIdx.x & 63, h = lane >> 5, l = lane & 31;
  int d = blockIdx.x * 8 + (threadIdx.x >> 6) * 2 + h;   // 12500 blocks x 8 = 100000 exact
  int start = offsets[d], end = offsets[d + 1];
  float dd = dinv[d], sl = dd * dd;
  uint2 su = xb[(size_t)d * 32 + l];
  float s0 = sl * blo(su.x), s1 = sl * bhi(su.x), s2 = sl * blo(su.y), s3 = sl * bhi(su.y);
  float t0 = 0.f, t1 = 0.f, t2 = 0.f, t3 = 0.f;

  for (int i = start; i < end; i += 8) {
    i32x2 e[8];
    #pragma unroll
    for (int k = 0; k < 8; ++k) e[k] = __builtin_nontemporal_load(&ep[i + k]);  // ≤7 past end: epair has slack
    #pragma unroll
    for (int k = 0; k < 8; ++k) {
      bool val = (i + k) < end;
      int idx  = val ? e[k].x : 0;
      float n  = val ? __int_as_float(e[k].y) : 0.f;
      uint2 r  = xb[(size_t)idx * 32 + l];
      if (k & 1) { t0 += n * blo(r.x); t1 += n * bhi(r.x); t2 += n * blo(r.y); t3 += n * bhi(r.y); }
      else       { s0 += n * blo(r.x); s1 += n * bhi(r.x); s2 += n * blo(r.y); s3 += n * bhi(r.y); }
    }
  }
  u32x2 o;
  o.x = (unsigned)f2bf(s0 + t0) | ((unsigned)f2bf(s1 + t1) << 16);
  o.y = (unsigned)f2bf(s2 + t2) | ((unsigned)f2bf(s3 + t3) << 16);
  __builtin_nontemporal_store(o, (u32x2*)(z1 + 2 * ((size_t)d * 32 + l)));
}

// ---------------- fused GEMM1+bias+relu+GEMM2 via bf16 MFMA ----------------
// 4 independent waves/block, each owns 64 rows (4 m-tiles). No __syncthreads. P emitted bf16 (nt).
#define HS_STRIDE 56   // ushorts; 112B rows: 16B-aligned b128 reads, worst 2-way conflict = free
__global__ __launch_bounds__(256) void k_fused_mfma(const unsigned short* __restrict__ z1b,
                                                    const unsigned short* __restrict__ W1F,
                                                    const float* __restrict__ b1,
                                                    const unsigned short* __restrict__ W2F,
                                                    unsigned short* __restrict__ Pb) {
  __shared__ unsigned short Hs[4][64 * HS_STRIDE];
  const int tid  = threadIdx.x;
  const int w    = tid >> 6, lane = tid & 63;
  const int c16  = lane & 15, quad = lane >> 4;
  const int mbase = blockIdx.x * 256 + w * 64;

  bf16x8 afrag[4][4];
  #pragma unroll
  for (int t = 0; t < 4; ++t) {
    int mrow = mbase + t * 16 + c16;
    int meff = (mrow < N_NODES) ? mrow : 0;
    const bf16x8* arow = (const bf16x8*)(z1b + (size_t)meff * IN_DIM + quad * 8);
    afrag[t][0] = arow[0];
    afrag[t][1] = arow[4];     // +32 ushorts
    afrag[t][2] = arow[8];
    afrag[t][3] = arow[12];
  }

  f32x4 pacc[4][3];
  #pragma unroll
  for (int t = 0; t < 4; ++t)
    #pragma unroll
    for (int ct = 0; ct < 3; ++ct) pacc[t][ct] = (f32x4){0.f, 0.f, 0.f, 0.f};

  const bf16x8* w1f = (const bf16x8*)W1F;
  const bf16x8* w2f = (const bf16x8*)W2F;
  unsigned short* hs = Hs[w];

  for (int g = 0; g < 16; ++g) {               // 32 H-cols per group
    #pragma unroll
    for (int nt = 0; nt < 2; ++nt) {
      int c = g * 2 + nt;                      // 16-col chunk
      bf16x8 bp0 = w1f[(c * 4 + 0) * 64 + lane];   // coalesced 1KB/wave
      bf16x8 bp1 = w1f[(c * 4 + 1) * 64 + lane];
      bf16x8 bp2 = w1f[(c * 4 + 2) * 64 + lane];
      bf16x8 bp3 = w1f[(c * 4 + 3) * 64 + lane];
      f32x4 h[4];
      #pragma unroll
      for (int t = 0; t < 4; ++t) h[t] = (f32x4){0.f, 0.f, 0.f, 0.f};
      #pragma unroll
      for (int t = 0; t < 4; ++t) h[t] = __builtin_amdgcn_mfma_f32_16x16x32_bf16(afrag[t][0], bp0, h[t], 0, 0, 0);
      #pragma unroll
      for (int t = 0; t < 4; ++t) h[t] = __builtin_amdgcn_mfma_f32_16x16x32_bf16(afrag[t][1], bp1, h[t], 0, 0, 0);
      #pragma unroll
      for (int t = 0; t < 4; ++t) h[t] = __builtin_amdgcn_mfma_f32_16x16x32_bf16(afrag[t][2], bp2, h[t], 0, 0, 0);
      #pragma unroll
      for (int t = 0; t < 4; ++t) h[t] = __builtin_amdgcn_mfma_f32_16x16x32_bf16(afrag[t][3], bp3, h[t], 0, 0, 0);
      float bias = b1[c * 16 + c16];
      #pragma unroll
      for (int t = 0; t < 4; ++t)
        #pragma unroll
        for (int r = 0; r < 4; ++r)            // C layout: col=c16, row=quad*4+r
          hs[(t * 16 + quad * 4 + r) * HS_STRIDE + nt * 16 + c16] = f2bf(fmaxf(h[t][r] + bias, 0.f));
    }
    bf16x8 hf[4];
    #pragma unroll
    for (int t = 0; t < 4; ++t)
      hf[t] = *(const bf16x8*)(hs + (t * 16 + c16) * HS_STRIDE + quad * 8);
    #pragma unroll
    for (int ct = 0; ct < 3; ++ct) {
      bf16x8 bf = w2f[(g * 3 + ct) * 64 + lane];   // coalesced
      #pragma unroll
      for (int t = 0; t < 4; ++t)
        pacc[t][ct] = __builtin_amdgcn_mfma_f32_16x16x32_bf16(hf[t], bf, pacc[t][ct], 0, 0, 0);
    }
  }

  #pragma unroll
  for (int t = 0; t < 4; ++t) {
    int mrow0 = mbase + t * 16 + quad * 4;
    #pragma unroll
    for (int ct = 0; ct < 3; ++ct) {
      int col = ct * 16 + c16;
      if (col < N_CLS) {
        #pragma unroll
        for (int r = 0; r < 4; ++r) {
          int m = mrow0 + r;
          if (m < N_NODES)
            __builtin_nontemporal_store(f2bf(pacc[t][ct][r]), &Pb[(size_t)m * N_CLS + col]);
        }
      }
    }
  }
}

// ---------------- layer-2 aggregation (gather bf16, 40-dim) + bias + log_softmax ----------------
// ONE node per 16-lane quarter; 10 active lanes x uint2 (4 packed classes) = 80B row.
// Branch-free 8-wide masked rounds; f32x4 nt output.
__global__ __launch_bounds__(256) void k_gather2_lsm(const uint2* __restrict__ Pu2,
                                                     const i32x2* __restrict__ ep,
                                                     const int* __restrict__ offsets,
                                                     const float* __restrict__ dinv, const float* __restrict__ b2,
                                                     float* __restrict__ out) {
  int lane = threadIdx.x & 63, q = lane >> 4, l = lane & 15;
  int d = blockIdx.x * 16 + (threadIdx.x >> 6) * 4 + q;   // 6250 blocks x 16 = 100000 exact
  bool act = l < 10;
  int lc = act ? l : 0;
  int start = offsets[d], end = offsets[d + 1];
  float dd = dinv[d], sl = dd * dd;

  uint2 su = Pu2[(size_t)d * 10 + lc];
  float s0 = sl * blo(su.x), s1 = sl * bhi(su.x), s2 = sl * blo(su.y), s3 = sl * bhi(su.y);
  float t0 = 0.f, t1 = 0.f, t2 = 0.f, t3 = 0.f;

  for (int i = start; i < end; i += 8) {
    i32x2 e[8];
    #pragma unroll
    for (int k = 0; k < 8; ++k) e[k] = __builtin_nontemporal_load(&ep[i + k]);
    #pragma unroll
    for (int k = 0; k < 8; ++k) {
      bool val = (i + k) < end;
      int idx  = val ? e[k].x : 0;
      float n  = val ? __int_as_float(e[k].y) : 0.f;
      uint2 u  = Pu2[(size_t)idx * 10 + lc];
      if (k & 1) { t0 += n * blo(u.x); t1 += n * bhi(u.x); t2 += n * blo(u.y); t3 += n * bhi(u.y); }
      else       { s0 += n * blo(u.x); s1 += n * bhi(u.x); s2 += n * blo(u.y); s3 += n * bhi(u.y); }
    }
  }

  float v0, v1, v2, v3;
  if (act) {
    float4 bb = ((const float4*)b2)[l];
    v0 = s0 + t0 + bb.x;
    v1 = s1 + t1 + bb.y;
    v2 = s2 + t2 + bb.z;
    v3 = s3 + t3 + bb.w;
  } else {
    v0 = v1 = v2 = v3 = -1e30f;
  }
  // log-softmax over 40 classes held by 10 lanes of this quarter (shuffles stay in-quarter)
  float m = fmaxf(fmaxf(v0, v1), fmaxf(v2, v3));
  #pragma unroll
  for (int off = 8; off > 0; off >>= 1) m = fmaxf(m, __shfl_xor(m, off, 64));
  float e = act ? (expf(v0 - m) + expf(v1 - m) + expf(v2 - m) + expf(v3 - m)) : 0.f;
  float s = e;
  #pragma unroll
  for (int off = 8; off > 0; off >>= 1) s += __shfl_xor(s, off, 64);
  float lse = m + logf(s);
  if (act) {
    f32x4 o = (f32x4){v0 - lse, v1 - lse, v2 - lse, v3 - lse};
    __builtin_nontemporal_store(o, (f32x4*)(out + (size_t)d * N_CLS + 4 * l));
  }
}

// ---------------- launcher ----------------
extern "C" void kernel_launch(void* const* d_in, const int* in_sizes, int n_in,
                              void* d_out, int out_size, void* d_ws, size_t ws_size,
                              hipStream_t stream) {
  const float* x  = (const float*)d_in[0];
  const int*   ei = (const int*)d_in[1];
  const int*  src = ei;                       // edge_index[0]
  const int*  dst = ei + N_EDGES;             // edge_index[1]
  const float* W1 = (const float*)d_in[2];
  const float* b1 = (const float*)d_in[3];
  const float* W2 = (const float*)d_in[4];
  const float* b2 = (const float*)d_in[5];
  float* out = (float*)d_out;

  // workspace layout (all 16B-aligned). Pb aliases xb2 (dead after k_gather1).
  float* dinv    = (float*)d_ws;                            // 131072 f
  int*   cnt     = (int*)(dinv + 131072);                   // 131072 i
  int*   offsets = cnt + 131072;                            // 131072 i (incl sentinel)
  int*   cursor  = offsets + 131072;                        // 131072 i
  unsigned* flags = (unsigned*)(cursor + 131072);           // 1024 u
  int2*  epair   = (int2*)(flags + 1024);                   // 500000 int2 (pad to 524288 — 8-wide overread safe)
  uint2* xb2     = (uint2*)(epair + 524288);                // 3.2M uint2 (25.6 MB)
  unsigned short* Pb = (unsigned short*)xb2;                // alias: 4M us (8 MB) — xb dead by then
  unsigned short* z1b = (unsigned short*)(xb2 + 3200000);   // 12.8M us (25.6 MB)
  unsigned short* W1F = z1b + (size_t)N_NODES * IN_DIM;     // 65536 us
  unsigned short* W2F = W1F + HID * IN_DIM;                 // 24576 us

  (void)hipMemsetAsync(cnt, 0, N_NODES * sizeof(int), stream);
  (void)hipMemsetAsync(flags, 0, 512 * sizeof(unsigned), stream);
  k_count_xbf<<<N_CNTB + N_XBFB, 256, 0, stream>>>(dst, cnt, x, (unsigned*)xb2);
  k_scan_prep<<<N_SBLK + N_PREPB, 256, 0, stream>>>(cnt, flags, offsets, cursor, dinv, W1, W2, W1F, W2F);
  k_fill <<<N_CNTB, 256, 0, stream>>>(src, dst, dinv, cursor, epair);
  k_gather1<<<N_NODES / 8, 256, 0, stream>>>(xb2, (const i32x2*)epair, offsets, dinv, (unsigned*)z1b);
  k_fused_mfma<<<(N_NODES + 255) / 256, 256, 0, stream>>>(z1b, W1F, b1, W2F, Pb);
  k_gather2_lsm<<<N_NODES / 16, 256, 0, stream>>>((const uint2*)Pb, (const i32x2*)epair, offsets, dinv, b2, out);
}